// Round 4
// baseline (1315.633 us; speedup 1.0000x reference)
//
#include <hip/hip_runtime.h>

// Problem constants (match reference setup_inputs)
#define NB    50000   // nodes
#define BB    64      // batch  (== wavefront size: lane = b)
#define DD    16      // neighbors per node
#define NDRVN 1000    // driver nodes

// ---------------------------------------------------------------------------
// Transpose x (B,N) -> z0 (N,B).
__global__ __launch_bounds__(256) void transpose_kernel(
    const float* __restrict__ x, float* __restrict__ xT)
{
    int tid = blockIdx.x * 256 + threadIdx.x;   // tid = n*64 + b
    int n = tid >> 6;
    int b = tid & 63;
    if (n < NB) xT[tid] = x[b * NB + n];
}

// ---------------------------------------------------------------------------
// One 5->5 conv1x3+relu layer for TWO nodes simultaneously (A and B).
// x-outer / channel-inner order keeps live values ~75/node (in columns die
// as x advances).  All 75 weights + 5 biases are wave-uniform -> SGPRs,
// loaded once per layer and consumed by both nodes' FMA streams; the A/B
// interleave gives every dependency chain a twin to hide FMA latency.
template<int WIN>
__device__ __forceinline__ void conv5x2(
    const float (&inA)[5][14], const float (&inB)[5][14],
    float (&outA)[5][14], float (&outB)[5][14],
    const float* __restrict__ w, const float* __restrict__ bias)
{
    constexpr int WOUT = WIN - 2;
    float wr[75];
#pragma unroll
    for (int t = 0; t < 75; ++t) wr[t] = w[t];
    float bb[5];
#pragma unroll
    for (int c = 0; c < 5; ++c) bb[c] = bias[c];

#pragma unroll
    for (int x = 0; x < WOUT; ++x) {
#pragma unroll
        for (int c = 0; c < 5; ++c) {
            float aA = bb[c], aB = bb[c];
#pragma unroll
            for (int ci = 0; ci < 5; ++ci) {
                aA = fmaf(wr[c * 15 + ci * 3 + 0], inA[ci][x + 0], aA);
                aB = fmaf(wr[c * 15 + ci * 3 + 0], inB[ci][x + 0], aB);
                aA = fmaf(wr[c * 15 + ci * 3 + 1], inA[ci][x + 1], aA);
                aB = fmaf(wr[c * 15 + ci * 3 + 1], inB[ci][x + 1], aB);
                aA = fmaf(wr[c * 15 + ci * 3 + 2], inA[ci][x + 2], aA);
                aB = fmaf(wr[c * 15 + ci * 3 + 2], inB[ci][x + 2], aB);
            }
            outA[c][x] = fmaxf(aA, 0.0f);
            outB[c][x] = fmaxf(aB, 0.0f);
        }
    }
}

// ---------------------------------------------------------------------------
// One full pass, TWO nodes per wave: gather 2x16 neighbors, run the 7-layer
// CNN on both, pair-average.  Wave w handles nodes 2w and 2w+1; lane = batch.
// z layout (N, B).  Stall sources (scalar weight-load waits, gather vmcnt,
// FMA dep chains) are amortized over 2x the FMA work vs the 1-node version
// (R3: 328us/pass at ~47% real VALU busy).
__global__ __launch_bounds__(256)
__attribute__((amdgpu_waves_per_eu(2, 2)))
void pass_kernel(
    const float* __restrict__ zin, float* __restrict__ zout,
    const int*  __restrict__ nidx,
    const float* __restrict__ w0, const float* __restrict__ b0,
    const float* __restrict__ w1, const float* __restrict__ b1,
    const float* __restrict__ w2, const float* __restrict__ b2,
    const float* __restrict__ w3, const float* __restrict__ b3,
    const float* __restrict__ w4, const float* __restrict__ b4,
    const float* __restrict__ w5, const float* __restrict__ b5,
    const float* __restrict__ w6, const float* __restrict__ b6)
{
    int lane   = threadIdx.x & 63;
    int waveid = blockIdx.x * 4 + (threadIdx.x >> 6);     // 25000 waves
    int n0 = __builtin_amdgcn_readfirstlane(waveid * 2);  // nodes n0, n0+1

    // Neighbor indices for both nodes: 32 contiguous ints -> s_loads.
    const int* ip = nidx + n0 * DD;

    // Gather: 32 fully-coalesced 256B loads (uniform base + lane*4).
    float gA[16], gB[16];
#pragma unroll
    for (int d = 0; d < 16; ++d) gA[d] = zin[(size_t)ip[d] * BB + lane];
#pragma unroll
    for (int d = 0; d < 16; ++d) gB[d] = zin[(size_t)ip[16 + d] * BB + lane];

    float haA[5][14], hbA[5][14];
    float haB[5][14], hbB[5][14];

    // Layer 0: 1 -> 5 channels, width 16 -> 14
    {
        float wr[15], bb[5];
#pragma unroll
        for (int t = 0; t < 15; ++t) wr[t] = w0[t];
#pragma unroll
        for (int c = 0; c < 5; ++c) bb[c] = b0[c];
#pragma unroll
        for (int x = 0; x < 14; ++x) {
#pragma unroll
            for (int c = 0; c < 5; ++c) {
                float aA = bb[c], aB = bb[c];
                aA = fmaf(wr[c * 3 + 0], gA[x + 0], aA);
                aB = fmaf(wr[c * 3 + 0], gB[x + 0], aB);
                aA = fmaf(wr[c * 3 + 1], gA[x + 1], aA);
                aB = fmaf(wr[c * 3 + 1], gB[x + 1], aB);
                aA = fmaf(wr[c * 3 + 2], gA[x + 2], aA);
                aB = fmaf(wr[c * 3 + 2], gB[x + 2], aB);
                haA[c][x] = fmaxf(aA, 0.0f);
                haB[c][x] = fmaxf(aB, 0.0f);
            }
        }
    }

    conv5x2<14>(haA, haB, hbA, hbB, w1, b1);   // 14 -> 12
    conv5x2<12>(hbA, hbB, haA, haB, w2, b2);   // 12 -> 10
    conv5x2<10>(haA, haB, hbA, hbB, w3, b3);   // 10 -> 8
    conv5x2<8> (hbA, hbB, haA, haB, w4, b4);   // 8  -> 6
    conv5x2<6> (haA, haB, hbA, hbB, w5, b5);   // 6  -> 4

    // Layer 6: 5 -> 1, width 4 -> 2, then pair-average.
    {
        float wr[15];
#pragma unroll
        for (int t = 0; t < 15; ++t) wr[t] = w6[t];
        float bias = b6[0];
        float t0A = bias, t1A = bias, t0B = bias, t1B = bias;
#pragma unroll
        for (int ci = 0; ci < 5; ++ci) {
            t0A = fmaf(wr[ci * 3 + 0], hbA[ci][0], t0A);
            t0B = fmaf(wr[ci * 3 + 0], hbB[ci][0], t0B);
            t0A = fmaf(wr[ci * 3 + 1], hbA[ci][1], t0A);
            t0B = fmaf(wr[ci * 3 + 1], hbB[ci][1], t0B);
            t0A = fmaf(wr[ci * 3 + 2], hbA[ci][2], t0A);
            t0B = fmaf(wr[ci * 3 + 2], hbB[ci][2], t0B);
            t1A = fmaf(wr[ci * 3 + 0], hbA[ci][1], t1A);
            t1B = fmaf(wr[ci * 3 + 0], hbB[ci][1], t1B);
            t1A = fmaf(wr[ci * 3 + 1], hbA[ci][2], t1A);
            t1B = fmaf(wr[ci * 3 + 1], hbB[ci][2], t1B);
            t1A = fmaf(wr[ci * 3 + 2], hbA[ci][3], t1A);
            t1B = fmaf(wr[ci * 3 + 2], hbB[ci][3], t1B);
        }
        float oA = 0.5f * (fmaxf(t0A, 0.0f) + fmaxf(t1A, 0.0f));
        float oB = 0.5f * (fmaxf(t0B, 0.0f) + fmaxf(t1B, 0.0f));
        zout[(size_t)n0 * BB + lane]        = oA;
        zout[(size_t)(n0 + 1) * BB + lane]  = oB;
    }
}

// ---------------------------------------------------------------------------
// Final driver gather: out[b, i] = z[driver_idx[i], b]   (out is (B, NDRV))
__global__ __launch_bounds__(256) void gather_out_kernel(
    const float* __restrict__ z, const int* __restrict__ didx,
    float* __restrict__ out)
{
    int i = blockIdx.x * 256 + threadIdx.x;
    if (i >= BB * NDRVN) return;
    int b = i / NDRVN;
    int k = i - b * NDRVN;
    out[i] = z[(size_t)didx[k] * BB + b];
}

// ---------------------------------------------------------------------------
extern "C" void kernel_launch(void* const* d_in, const int* in_sizes, int n_in,
                              void* d_out, int out_size, void* d_ws, size_t ws_size,
                              hipStream_t stream)
{
    const float* x    = (const float*)d_in[0];
    const int*   nidx = (const int*)  d_in[1];
    const int*   didx = (const int*)  d_in[2];
    const float* w[7];
    const float* b[7];
    for (int i = 0; i < 7; ++i) {
        w[i] = (const float*)d_in[3 + 2 * i];
        b[i] = (const float*)d_in[4 + 2 * i];
    }

    // Workspace: two ping-pong z buffers in (N, B) layout, 12.8 MB each.
    float* z0 = (float*)d_ws;
    float* z1 = z0 + (size_t)NB * BB;

    const int tblocks = (NB * BB) / 256;          // 12500 (transpose)
    const int pblocks = NB / 8;                   // 6250: 4 waves x 2 nodes

    transpose_kernel<<<tblocks, 256, 0, stream>>>(x, z0);

    pass_kernel<<<pblocks, 256, 0, stream>>>(z0, z1, nidx,
        w[0], b[0], w[1], b[1], w[2], b[2], w[3], b[3],
        w[4], b[4], w[5], b[5], w[6], b[6]);
    pass_kernel<<<pblocks, 256, 0, stream>>>(z1, z0, nidx,
        w[0], b[0], w[1], b[1], w[2], b[2], w[3], b[3],
        w[4], b[4], w[5], b[5], w[6], b[6]);
    pass_kernel<<<pblocks, 256, 0, stream>>>(z0, z1, nidx,
        w[0], b[0], w[1], b[1], w[2], b[2], w[3], b[3],
        w[4], b[4], w[5], b[5], w[6], b[6]);
    pass_kernel<<<pblocks, 256, 0, stream>>>(z1, z0, nidx,
        w[0], b[0], w[1], b[1], w[2], b[2], w[3], b[3],
        w[4], b[4], w[5], b[5], w[6], b[6]);

    gather_out_kernel<<<(BB * NDRVN + 255) / 256, 256, 0, stream>>>(z0, didx, (float*)d_out);
}

// Round 5
// 988.442 us; speedup vs baseline: 1.3310x; 1.3310x over previous
//
#include <hip/hip_runtime.h>

// Problem constants (match reference setup_inputs)
#define NB    50000   // nodes
#define BB    64      // batch  (== wavefront size: lane = b)
#define DD    16      // neighbors per node
#define NDRVN 1000    // driver nodes

// ---------------------------------------------------------------------------
// Force a (uniform) value into a VGPR.  R1-R4 all ran the inner loop as
// v_fma_f32 vdst, sgpr_weight, vgpr, vgpr (VOP3 + SGPR broadcast) and all
// pinned at ~4.3 cyc/VALU-inst regardless of occupancy/ILP.  Theory: the
// SGPR-broadcast / VOP3 operand path halves fma issue rate.  Pinning weights
// to VGPRs lets the compiler emit all-VGPR v_fmac_f32 (VOP2).
__device__ __forceinline__ float vg(float s) {
    asm("" : "+v"(s));
    return s;
}

// ---------------------------------------------------------------------------
// Transpose x (B,N) -> z0 (N,B).
__global__ __launch_bounds__(256) void transpose_kernel(
    const float* __restrict__ x, float* __restrict__ xT)
{
    int tid = blockIdx.x * 256 + threadIdx.x;   // tid = n*64 + b
    int n = tid >> 6;
    int b = tid & 63;
    if (n < NB) xT[tid] = x[b * NB + n];
}

// ---------------------------------------------------------------------------
// One 5->5 conv1x3 + relu layer, fully unrolled.  Weights/bias are loaded
// scalar (uniform address) then pinned into VGPRs once per (c) row; the
// 15-fma accumulation chain is then pure VOP2 v_fmac_f32.
template<int WOUT>
__device__ __forceinline__ void conv5(const float (&in)[5][14], float (&out)[5][14],
                                      const float* __restrict__ w,
                                      const float* __restrict__ bias)
{
#pragma unroll
    for (int c = 0; c < 5; ++c) {
        float wr[15];
#pragma unroll
        for (int t = 0; t < 15; ++t) wr[t] = vg(w[c * 15 + t]);
        float bc = vg(bias[c]);
#pragma unroll
        for (int x = 0; x < WOUT; ++x) {
            float acc = bc;
#pragma unroll
            for (int ci = 0; ci < 5; ++ci) {
                acc = fmaf(wr[ci * 3 + 0], in[ci][x + 0], acc);
                acc = fmaf(wr[ci * 3 + 1], in[ci][x + 1], acc);
                acc = fmaf(wr[ci * 3 + 2], in[ci][x + 2], acc);
            }
            out[c][x] = fmaxf(acc, 0.0f);
        }
    }
}

// ---------------------------------------------------------------------------
// One full pass: gather 16 neighbors, run the 7-layer CNN, pair-average.
// Wave = one node n (uniform), lane = batch index b.  z layout (N, B).
// Identical structure to R3 (328 us/pass) -- ONLY change is VGPR-pinned
// weights/biases (clean A/B on the operand-path theory).
__global__ __launch_bounds__(256)
__attribute__((amdgpu_waves_per_eu(2, 2)))
void pass_kernel(
    const float* __restrict__ zin, float* __restrict__ zout,
    const int*  __restrict__ nidx,
    const float* __restrict__ w0, const float* __restrict__ b0,
    const float* __restrict__ w1, const float* __restrict__ b1,
    const float* __restrict__ w2, const float* __restrict__ b2,
    const float* __restrict__ w3, const float* __restrict__ b3,
    const float* __restrict__ w4, const float* __restrict__ b4,
    const float* __restrict__ w5, const float* __restrict__ b5,
    const float* __restrict__ w6, const float* __restrict__ b6)
{
    int tid  = blockIdx.x * 256 + threadIdx.x;
    int lane = tid & 63;
    // grid is exact (N*B == 12500*256) so every wave is full; force n uniform
    int n = __builtin_amdgcn_readfirstlane(tid >> 6);

    // Neighbor indices: wave-uniform addresses -> s_load into SGPRs.
    const int* ip = nidx + n * DD;

    // Gather: 16 fully-coalesced 256B loads (uniform base + lane*4).
    float g[16];
#pragma unroll
    for (int d = 0; d < 16; ++d) {
        int j = ip[d];
        g[d] = zin[(size_t)j * BB + lane];
    }

    float ha[5][14], hb[5][14];

    // Layer 0: 1 -> 5 channels, width 16 -> 14
#pragma unroll
    for (int c = 0; c < 5; ++c) {
        float wa = vg(w0[c * 3 + 0]), wb = vg(w0[c * 3 + 1]), wc = vg(w0[c * 3 + 2]);
        float bc = vg(b0[c]);
#pragma unroll
        for (int x = 0; x < 14; ++x) {
            float acc = bc;
            acc = fmaf(wa, g[x + 0], acc);
            acc = fmaf(wb, g[x + 1], acc);
            acc = fmaf(wc, g[x + 2], acc);
            ha[c][x] = fmaxf(acc, 0.0f);
        }
    }

    conv5<12>(ha, hb, w1, b1);   // 14 -> 12
    conv5<10>(hb, ha, w2, b2);   // 12 -> 10
    conv5<8> (ha, hb, w3, b3);   // 10 -> 8
    conv5<6> (hb, ha, w4, b4);   // 8  -> 6
    conv5<4> (ha, hb, w5, b5);   // 6  -> 4

    // Layer 6: 5 -> 1, width 4 -> 2
    float bias6 = vg(b6[0]);
    float t0 = bias6, t1 = bias6;
#pragma unroll
    for (int ci = 0; ci < 5; ++ci) {
        float wa = vg(w6[ci * 3 + 0]), wb = vg(w6[ci * 3 + 1]), wc = vg(w6[ci * 3 + 2]);
        t0 = fmaf(wa, hb[ci][0], t0);
        t0 = fmaf(wb, hb[ci][1], t0);
        t0 = fmaf(wc, hb[ci][2], t0);
        t1 = fmaf(wa, hb[ci][1], t1);
        t1 = fmaf(wb, hb[ci][2], t1);
        t1 = fmaf(wc, hb[ci][3], t1);
    }
    t0 = fmaxf(t0, 0.0f);
    t1 = fmaxf(t1, 0.0f);

    zout[(size_t)n * BB + lane] = 0.5f * (t0 + t1);
}

// ---------------------------------------------------------------------------
// Final driver gather: out[b, i] = z[driver_idx[i], b]   (out is (B, NDRV))
__global__ __launch_bounds__(256) void gather_out_kernel(
    const float* __restrict__ z, const int* __restrict__ didx,
    float* __restrict__ out)
{
    int i = blockIdx.x * 256 + threadIdx.x;
    if (i >= BB * NDRVN) return;
    int b = i / NDRVN;
    int k = i - b * NDRVN;
    out[i] = z[(size_t)didx[k] * BB + b];
}

// ---------------------------------------------------------------------------
extern "C" void kernel_launch(void* const* d_in, const int* in_sizes, int n_in,
                              void* d_out, int out_size, void* d_ws, size_t ws_size,
                              hipStream_t stream)
{
    const float* x    = (const float*)d_in[0];
    const int*   nidx = (const int*)  d_in[1];
    const int*   didx = (const int*)  d_in[2];
    const float* w[7];
    const float* b[7];
    for (int i = 0; i < 7; ++i) {
        w[i] = (const float*)d_in[3 + 2 * i];
        b[i] = (const float*)d_in[4 + 2 * i];
    }

    // Workspace: two ping-pong z buffers in (N, B) layout, 12.8 MB each.
    float* z0 = (float*)d_ws;
    float* z1 = z0 + (size_t)NB * BB;

    const int blocks = (NB * BB) / 256;   // 12500, exact

    transpose_kernel<<<blocks, 256, 0, stream>>>(x, z0);

    pass_kernel<<<blocks, 256, 0, stream>>>(z0, z1, nidx,
        w[0], b[0], w[1], b[1], w[2], b[2], w[3], b[3],
        w[4], b[4], w[5], b[5], w[6], b[6]);
    pass_kernel<<<blocks, 256, 0, stream>>>(z1, z0, nidx,
        w[0], b[0], w[1], b[1], w[2], b[2], w[3], b[3],
        w[4], b[4], w[5], b[5], w[6], b[6]);
    pass_kernel<<<blocks, 256, 0, stream>>>(z0, z1, nidx,
        w[0], b[0], w[1], b[1], w[2], b[2], w[3], b[3],
        w[4], b[4], w[5], b[5], w[6], b[6]);
    pass_kernel<<<blocks, 256, 0, stream>>>(z1, z0, nidx,
        w[0], b[0], w[1], b[1], w[2], b[2], w[3], b[3],
        w[4], b[4], w[5], b[5], w[6], b[6]);

    gather_out_kernel<<<(BB * NDRVN + 255) / 256, 256, 0, stream>>>(z0, didx, (float*)d_out);
}

// Round 6
// 958.950 us; speedup vs baseline: 1.3720x; 1.0308x over previous
//
#include <hip/hip_runtime.h>

// Problem constants (match reference setup_inputs)
#define NB    50000   // nodes
#define BB    64      // batch  (== wavefront size: lane = b)
#define DD    16      // neighbors per node
#define NDRVN 1000    // driver nodes

// ---------------------------------------------------------------------------
// Force a (uniform) value into a VGPR.  Measured (R4->R5): v_fma_f32 with an
// SGPR broadcast operand issues at ~half the all-VGPR v_fmac_f32 rate on
// gfx950; pinning weights to VGPRs cut a pass 328 -> 265 us.
__device__ __forceinline__ float vg(float s) {
    asm("" : "+v"(s));
    return s;
}

// ---------------------------------------------------------------------------
// Transpose x (B,N) -> z0 (N,B).
__global__ __launch_bounds__(256) void transpose_kernel(
    const float* __restrict__ x, float* __restrict__ xT)
{
    int tid = blockIdx.x * 256 + threadIdx.x;   // tid = n*64 + b
    int n = tid >> 6;
    int b = tid & 63;
    if (n < NB) xT[tid] = x[b * NB + n];
}

// ---------------------------------------------------------------------------
// One 5->5 conv1x3 + relu layer, fully unrolled.  Weights/bias loaded scalar
// (uniform address) then pinned into VGPRs once per output-channel row; the
// 15-fma accumulation chain is then pure VOP2 v_fmac_f32.
template<int WOUT>
__device__ __forceinline__ void conv5(const float (&in)[5][14], float (&out)[5][14],
                                      const float* __restrict__ w,
                                      const float* __restrict__ bias)
{
#pragma unroll
    for (int c = 0; c < 5; ++c) {
        float wr[15];
#pragma unroll
        for (int t = 0; t < 15; ++t) wr[t] = vg(w[c * 15 + t]);
        float bc = vg(bias[c]);
#pragma unroll
        for (int x = 0; x < WOUT; ++x) {
            float acc = bc;
#pragma unroll
            for (int ci = 0; ci < 5; ++ci) {
                acc = fmaf(wr[ci * 3 + 0], in[ci][x + 0], acc);
                acc = fmaf(wr[ci * 3 + 1], in[ci][x + 1], acc);
                acc = fmaf(wr[ci * 3 + 2], in[ci][x + 2], acc);
            }
            out[c][x] = fmaxf(acc, 0.0f);
        }
    }
}

// ---------------------------------------------------------------------------
// One full pass: gather 16 neighbors, run the 7-layer CNN, pair-average.
// Wave = one node n (uniform), lane = batch index b.  z layout (N, B).
// R5 == this code with waves_per_eu(2,2) at 265 us/pass, ~69% real issue
// occupancy.  Only change: allow 4 waves/EU (VGPR 88 fits 4x128 budget) to
// hide layer-boundary scalar-load waits + fmac dep-chain latency.
__global__ __launch_bounds__(256)
__attribute__((amdgpu_waves_per_eu(4, 4)))
void pass_kernel(
    const float* __restrict__ zin, float* __restrict__ zout,
    const int*  __restrict__ nidx,
    const float* __restrict__ w0, const float* __restrict__ b0,
    const float* __restrict__ w1, const float* __restrict__ b1,
    const float* __restrict__ w2, const float* __restrict__ b2,
    const float* __restrict__ w3, const float* __restrict__ b3,
    const float* __restrict__ w4, const float* __restrict__ b4,
    const float* __restrict__ w5, const float* __restrict__ b5,
    const float* __restrict__ w6, const float* __restrict__ b6)
{
    int tid  = blockIdx.x * 256 + threadIdx.x;
    int lane = tid & 63;
    // grid is exact (N*B == 12500*256) so every wave is full; force n uniform
    int n = __builtin_amdgcn_readfirstlane(tid >> 6);

    // Neighbor indices: wave-uniform addresses -> s_load into SGPRs.
    const int* ip = nidx + n * DD;

    // Gather: 16 fully-coalesced 256B loads (uniform base + lane*4).
    float g[16];
#pragma unroll
    for (int d = 0; d < 16; ++d) {
        int j = ip[d];
        g[d] = zin[(size_t)j * BB + lane];
    }

    float ha[5][14], hb[5][14];

    // Layer 0: 1 -> 5 channels, width 16 -> 14
#pragma unroll
    for (int c = 0; c < 5; ++c) {
        float wa = vg(w0[c * 3 + 0]), wb = vg(w0[c * 3 + 1]), wc = vg(w0[c * 3 + 2]);
        float bc = vg(b0[c]);
#pragma unroll
        for (int x = 0; x < 14; ++x) {
            float acc = bc;
            acc = fmaf(wa, g[x + 0], acc);
            acc = fmaf(wb, g[x + 1], acc);
            acc = fmaf(wc, g[x + 2], acc);
            ha[c][x] = fmaxf(acc, 0.0f);
        }
    }

    conv5<12>(ha, hb, w1, b1);   // 14 -> 12
    conv5<10>(hb, ha, w2, b2);   // 12 -> 10
    conv5<8> (ha, hb, w3, b3);   // 10 -> 8
    conv5<6> (hb, ha, w4, b4);   // 8  -> 6
    conv5<4> (ha, hb, w5, b5);   // 6  -> 4

    // Layer 6: 5 -> 1, width 4 -> 2
    float bias6 = vg(b6[0]);
    float t0 = bias6, t1 = bias6;
#pragma unroll
    for (int ci = 0; ci < 5; ++ci) {
        float wa = vg(w6[ci * 3 + 0]), wb = vg(w6[ci * 3 + 1]), wc = vg(w6[ci * 3 + 2]);
        t0 = fmaf(wa, hb[ci][0], t0);
        t0 = fmaf(wb, hb[ci][1], t0);
        t0 = fmaf(wc, hb[ci][2], t0);
        t1 = fmaf(wa, hb[ci][1], t1);
        t1 = fmaf(wb, hb[ci][2], t1);
        t1 = fmaf(wc, hb[ci][3], t1);
    }
    t0 = fmaxf(t0, 0.0f);
    t1 = fmaxf(t1, 0.0f);

    zout[(size_t)n * BB + lane] = 0.5f * (t0 + t1);
}

// ---------------------------------------------------------------------------
// Final driver gather: out[b, i] = z[driver_idx[i], b]   (out is (B, NDRV))
__global__ __launch_bounds__(256) void gather_out_kernel(
    const float* __restrict__ z, const int* __restrict__ didx,
    float* __restrict__ out)
{
    int i = blockIdx.x * 256 + threadIdx.x;
    if (i >= BB * NDRVN) return;
    int b = i / NDRVN;
    int k = i - b * NDRVN;
    out[i] = z[(size_t)didx[k] * BB + b];
}

// ---------------------------------------------------------------------------
extern "C" void kernel_launch(void* const* d_in, const int* in_sizes, int n_in,
                              void* d_out, int out_size, void* d_ws, size_t ws_size,
                              hipStream_t stream)
{
    const float* x    = (const float*)d_in[0];
    const int*   nidx = (const int*)  d_in[1];
    const int*   didx = (const int*)  d_in[2];
    const float* w[7];
    const float* b[7];
    for (int i = 0; i < 7; ++i) {
        w[i] = (const float*)d_in[3 + 2 * i];
        b[i] = (const float*)d_in[4 + 2 * i];
    }

    // Workspace: two ping-pong z buffers in (N, B) layout, 12.8 MB each.
    float* z0 = (float*)d_ws;
    float* z1 = z0 + (size_t)NB * BB;

    const int blocks = (NB * BB) / 256;   // 12500, exact

    transpose_kernel<<<blocks, 256, 0, stream>>>(x, z0);

    pass_kernel<<<blocks, 256, 0, stream>>>(z0, z1, nidx,
        w[0], b[0], w[1], b[1], w[2], b[2], w[3], b[3],
        w[4], b[4], w[5], b[5], w[6], b[6]);
    pass_kernel<<<blocks, 256, 0, stream>>>(z1, z0, nidx,
        w[0], b[0], w[1], b[1], w[2], b[2], w[3], b[3],
        w[4], b[4], w[5], b[5], w[6], b[6]);
    pass_kernel<<<blocks, 256, 0, stream>>>(z0, z1, nidx,
        w[0], b[0], w[1], b[1], w[2], b[2], w[3], b[3],
        w[4], b[4], w[5], b[5], w[6], b[6]);
    pass_kernel<<<blocks, 256, 0, stream>>>(z1, z0, nidx,
        w[0], b[0], w[1], b[1], w[2], b[2], w[3], b[3],
        w[4], b[4], w[5], b[5], w[6], b[6]);

    gather_out_kernel<<<(BB * NDRVN + 255) / 256, 256, 0, stream>>>(z0, didx, (float*)d_out);
}

// Round 7
// 896.931 us; speedup vs baseline: 1.4668x; 1.0691x over previous
//
#include <hip/hip_runtime.h>

// Problem constants (match reference setup_inputs)
#define NB    50000   // nodes
#define BB    64      // batch  (== wavefront size: lane = b)
#define DD    16      // neighbors per node
#define NDRVN 1000    // driver nodes

// ---------------------------------------------------------------------------
// Force a (uniform) value into a VGPR.  Measured (R4->R5): v_fma_f32 with an
// SGPR broadcast operand issues at ~half the all-VGPR v_fmac_f32 rate on
// gfx950; pinning weights to VGPRs cut a pass 328 -> 265 us.
__device__ __forceinline__ float vg(float s) {
    asm("" : "+v"(s));
    return s;
}

// ---------------------------------------------------------------------------
// Transpose x (B,N) -> z0 (N,B).
__global__ __launch_bounds__(256) void transpose_kernel(
    const float* __restrict__ x, float* __restrict__ xT)
{
    int tid = blockIdx.x * 256 + threadIdx.x;   // tid = n*64 + b
    int n = tid >> 6;
    int b = tid & 63;
    if (n < NB) xT[tid] = x[b * NB + n];
}

// ---------------------------------------------------------------------------
// One 5->5 conv1x3 + relu layer, fully unrolled.  Weights/bias loaded scalar
// (uniform address) then pinned into VGPRs once per output-channel row; the
// 15-fma accumulation chain is then pure VOP2 v_fmac_f32.
template<int WOUT>
__device__ __forceinline__ void conv5(const float (&in)[5][14], float (&out)[5][14],
                                      const float* __restrict__ w,
                                      const float* __restrict__ bias)
{
#pragma unroll
    for (int c = 0; c < 5; ++c) {
        float wr[15];
#pragma unroll
        for (int t = 0; t < 15; ++t) wr[t] = vg(w[c * 15 + t]);
        float bc = vg(bias[c]);
#pragma unroll
        for (int x = 0; x < WOUT; ++x) {
            float acc = bc;
#pragma unroll
            for (int ci = 0; ci < 5; ++ci) {
                acc = fmaf(wr[ci * 3 + 0], in[ci][x + 0], acc);
                acc = fmaf(wr[ci * 3 + 1], in[ci][x + 1], acc);
                acc = fmaf(wr[ci * 3 + 2], in[ci][x + 2], acc);
            }
            out[c][x] = fmaxf(acc, 0.0f);
        }
    }
}

// ---------------------------------------------------------------------------
// One full pass: gather 16 neighbors, run the 7-layer CNN, pair-average.
// Wave = one node n (uniform), lane = batch index b.  z layout (N, B).
//
// waves_per_eu(2,8): min=2 keeps the RA budget at 256 so codegen stays the
// spill-free ~88-VGPR version (R5); max=8 removes R5's artificial occupancy
// cap so hardware runs 512/88 -> 5 waves/EU.  (R6's (4,4) forced VGPR=64 +
// 197 MB/pass scratch spill traffic -- faster than R5 via TLP, but wasteful.)
__global__ __launch_bounds__(256)
__attribute__((amdgpu_waves_per_eu(2, 8)))
void pass_kernel(
    const float* __restrict__ zin, float* __restrict__ zout,
    const int*  __restrict__ nidx,
    const float* __restrict__ w0, const float* __restrict__ b0,
    const float* __restrict__ w1, const float* __restrict__ b1,
    const float* __restrict__ w2, const float* __restrict__ b2,
    const float* __restrict__ w3, const float* __restrict__ b3,
    const float* __restrict__ w4, const float* __restrict__ b4,
    const float* __restrict__ w5, const float* __restrict__ b5,
    const float* __restrict__ w6, const float* __restrict__ b6)
{
    int tid  = blockIdx.x * 256 + threadIdx.x;
    int lane = tid & 63;
    // grid is exact (N*B == 12500*256) so every wave is full; force n uniform
    int n = __builtin_amdgcn_readfirstlane(tid >> 6);

    // Neighbor indices: wave-uniform addresses -> s_load into SGPRs.
    const int* ip = nidx + n * DD;

    // Gather: 16 fully-coalesced 256B loads (uniform base + lane*4).
    float g[16];
#pragma unroll
    for (int d = 0; d < 16; ++d) {
        int j = ip[d];
        g[d] = zin[(size_t)j * BB + lane];
    }

    float ha[5][14], hb[5][14];

    // Layer 0: 1 -> 5 channels, width 16 -> 14
#pragma unroll
    for (int c = 0; c < 5; ++c) {
        float wa = vg(w0[c * 3 + 0]), wb = vg(w0[c * 3 + 1]), wc = vg(w0[c * 3 + 2]);
        float bc = vg(b0[c]);
#pragma unroll
        for (int x = 0; x < 14; ++x) {
            float acc = bc;
            acc = fmaf(wa, g[x + 0], acc);
            acc = fmaf(wb, g[x + 1], acc);
            acc = fmaf(wc, g[x + 2], acc);
            ha[c][x] = fmaxf(acc, 0.0f);
        }
    }

    conv5<12>(ha, hb, w1, b1);   // 14 -> 12
    conv5<10>(hb, ha, w2, b2);   // 12 -> 10
    conv5<8> (ha, hb, w3, b3);   // 10 -> 8
    conv5<6> (hb, ha, w4, b4);   // 8  -> 6
    conv5<4> (ha, hb, w5, b5);   // 6  -> 4

    // Layer 6: 5 -> 1, width 4 -> 2
    float bias6 = vg(b6[0]);
    float t0 = bias6, t1 = bias6;
#pragma unroll
    for (int ci = 0; ci < 5; ++ci) {
        float wa = vg(w6[ci * 3 + 0]), wb = vg(w6[ci * 3 + 1]), wc = vg(w6[ci * 3 + 2]);
        t0 = fmaf(wa, hb[ci][0], t0);
        t0 = fmaf(wb, hb[ci][1], t0);
        t0 = fmaf(wc, hb[ci][2], t0);
        t1 = fmaf(wa, hb[ci][1], t1);
        t1 = fmaf(wb, hb[ci][2], t1);
        t1 = fmaf(wc, hb[ci][3], t1);
    }
    t0 = fmaxf(t0, 0.0f);
    t1 = fmaxf(t1, 0.0f);

    zout[(size_t)n * BB + lane] = 0.5f * (t0 + t1);
}

// ---------------------------------------------------------------------------
// Final driver gather: out[b, i] = z[driver_idx[i], b]   (out is (B, NDRV))
__global__ __launch_bounds__(256) void gather_out_kernel(
    const float* __restrict__ z, const int* __restrict__ didx,
    float* __restrict__ out)
{
    int i = blockIdx.x * 256 + threadIdx.x;
    if (i >= BB * NDRVN) return;
    int b = i / NDRVN;
    int k = i - b * NDRVN;
    out[i] = z[(size_t)didx[k] * BB + b];
}

// ---------------------------------------------------------------------------
extern "C" void kernel_launch(void* const* d_in, const int* in_sizes, int n_in,
                              void* d_out, int out_size, void* d_ws, size_t ws_size,
                              hipStream_t stream)
{
    const float* x    = (const float*)d_in[0];
    const int*   nidx = (const int*)  d_in[1];
    const int*   didx = (const int*)  d_in[2];
    const float* w[7];
    const float* b[7];
    for (int i = 0; i < 7; ++i) {
        w[i] = (const float*)d_in[3 + 2 * i];
        b[i] = (const float*)d_in[4 + 2 * i];
    }

    // Workspace: two ping-pong z buffers in (N, B) layout, 12.8 MB each.
    float* z0 = (float*)d_ws;
    float* z1 = z0 + (size_t)NB * BB;

    const int blocks = (NB * BB) / 256;   // 12500, exact

    transpose_kernel<<<blocks, 256, 0, stream>>>(x, z0);

    pass_kernel<<<blocks, 256, 0, stream>>>(z0, z1, nidx,
        w[0], b[0], w[1], b[1], w[2], b[2], w[3], b[3],
        w[4], b[4], w[5], b[5], w[6], b[6]);
    pass_kernel<<<blocks, 256, 0, stream>>>(z1, z0, nidx,
        w[0], b[0], w[1], b[1], w[2], b[2], w[3], b[3],
        w[4], b[4], w[5], b[5], w[6], b[6]);
    pass_kernel<<<blocks, 256, 0, stream>>>(z0, z1, nidx,
        w[0], b[0], w[1], b[1], w[2], b[2], w[3], b[3],
        w[4], b[4], w[5], b[5], w[6], b[6]);
    pass_kernel<<<blocks, 256, 0, stream>>>(z1, z0, nidx,
        w[0], b[0], w[1], b[1], w[2], b[2], w[3], b[3],
        w[4], b[4], w[5], b[5], w[6], b[6]);

    gather_out_kernel<<<(BB * NDRVN + 255) / 256, 256, 0, stream>>>(z0, didx, (float*)d_out);
}

// Round 8
// 896.262 us; speedup vs baseline: 1.4679x; 1.0007x over previous
//
#include <hip/hip_runtime.h>

// Problem constants (match reference setup_inputs)
#define NB    50000   // nodes
#define BB    64      // batch  (== wavefront size: lane = b)
#define DD    16      // neighbors per node
#define NDRVN 1000    // driver nodes

typedef float f2 __attribute__((ext_vector_type(2)));

// ---------------------------------------------------------------------------
// Force a (uniform) value into a VGPR.  Measured (R4->R5): fma with an SGPR
// broadcast operand issues at ~half the all-VGPR rate on gfx950.
__device__ __forceinline__ float vg(float s) {
    asm("" : "+v"(s));
    return s;
}

__device__ __forceinline__ f2 pf(f2 a, f2 b, f2 c) {
    return __builtin_elementwise_fma(a, b, c);   // -> v_pk_fma_f32
}
__device__ __forceinline__ f2 relu2(f2 a) {
    return __builtin_elementwise_max(a, (f2)0.0f);  // -> v_pk_max_f32
}
__device__ __forceinline__ f2 splat(float s) {
    float v = vg(s);
    return (f2){v, v};
}

// ---------------------------------------------------------------------------
// Transpose x (B,N) -> z0 (N,B).
__global__ __launch_bounds__(256) void transpose_kernel(
    const float* __restrict__ x, float* __restrict__ xT)
{
    int tid = blockIdx.x * 256 + threadIdx.x;   // tid = n*64 + b
    int n = tid >> 6;
    int b = tid & 63;
    if (n < NB) xT[tid] = x[b * NB + n];
}

// ---------------------------------------------------------------------------
// One 5->5 conv1x3+relu layer for TWO nodes packed as f2 (.x=node A, .y=B).
// x-outer / channel-inner: in-columns die as out-columns are produced, so
// data liveness stays ~5*WIN f2.  75 weight splats pinned in VGPRs.
template<int WIN>
__device__ __forceinline__ void conv5p(const f2 (&in)[5][14], f2 (&out)[5][14],
                                       const float* __restrict__ w,
                                       const float* __restrict__ bias)
{
    constexpr int WOUT = WIN - 2;
    f2 wr[75];
#pragma unroll
    for (int t = 0; t < 75; ++t) wr[t] = splat(w[t]);
    f2 bb[5];
#pragma unroll
    for (int c = 0; c < 5; ++c) bb[c] = splat(bias[c]);

#pragma unroll
    for (int x = 0; x < WOUT; ++x) {
#pragma unroll
        for (int c = 0; c < 5; ++c) {
            f2 acc = bb[c];
#pragma unroll
            for (int ci = 0; ci < 5; ++ci) {
                acc = pf(wr[c * 15 + ci * 3 + 0], in[ci][x + 0], acc);
                acc = pf(wr[c * 15 + ci * 3 + 1], in[ci][x + 1], acc);
                acc = pf(wr[c * 15 + ci * 3 + 2], in[ci][x + 2], acc);
            }
            out[c][x] = relu2(acc);
        }
    }
}

// ---------------------------------------------------------------------------
// One full pass, TWO nodes per wave packed into f2 lanes: gather 2x16
// neighbors into pairs, run the 7-layer CNN with v_pk_fma_f32 (2 FMA/inst),
// pair-average, store both nodes.  Wave w -> nodes 2w, 2w+1; lane = batch.
__global__ __launch_bounds__(256)
__attribute__((amdgpu_waves_per_eu(2, 8)))
void pass_kernel(
    const float* __restrict__ zin, float* __restrict__ zout,
    const int*  __restrict__ nidx,
    const float* __restrict__ w0, const float* __restrict__ b0,
    const float* __restrict__ w1, const float* __restrict__ b1,
    const float* __restrict__ w2, const float* __restrict__ b2,
    const float* __restrict__ w3, const float* __restrict__ b3,
    const float* __restrict__ w4, const float* __restrict__ b4,
    const float* __restrict__ w5, const float* __restrict__ b5,
    const float* __restrict__ w6, const float* __restrict__ b6)
{
    int lane   = threadIdx.x & 63;
    int waveid = blockIdx.x * 4 + (threadIdx.x >> 6);     // 25000 waves
    int n0 = __builtin_amdgcn_readfirstlane(waveid * 2);  // nodes n0, n0+1

    // Neighbor indices for both nodes: 32 contiguous ints -> s_loads.
    const int* ip = nidx + n0 * DD;

    // Gather both nodes' neighborhoods into f2 pairs (.x = A, .y = B).
    f2 g[16];
#pragma unroll
    for (int d = 0; d < 16; ++d) {
        float a = zin[(size_t)ip[d]      * BB + lane];
        float b = zin[(size_t)ip[16 + d] * BB + lane];
        g[d] = (f2){a, b};
    }

    f2 ha[5][14], hb[5][14];

    // Layer 0: 1 -> 5 channels, width 16 -> 14
    {
        f2 wr[15], bb[5];
#pragma unroll
        for (int t = 0; t < 15; ++t) wr[t] = splat(w0[t]);
#pragma unroll
        for (int c = 0; c < 5; ++c) bb[c] = splat(b0[c]);
#pragma unroll
        for (int x = 0; x < 14; ++x) {
#pragma unroll
            for (int c = 0; c < 5; ++c) {
                f2 acc = bb[c];
                acc = pf(wr[c * 3 + 0], g[x + 0], acc);
                acc = pf(wr[c * 3 + 1], g[x + 1], acc);
                acc = pf(wr[c * 3 + 2], g[x + 2], acc);
                ha[c][x] = relu2(acc);
            }
        }
    }

    conv5p<14>(ha, hb, w1, b1);   // 14 -> 12
    conv5p<12>(hb, ha, w2, b2);   // 12 -> 10
    conv5p<10>(ha, hb, w3, b3);   // 10 -> 8
    conv5p<8> (hb, ha, w4, b4);   // 8  -> 6
    conv5p<6> (ha, hb, w5, b5);   // 6  -> 4

    // Layer 6: 5 -> 1, width 4 -> 2, then pair-average.
    {
        f2 wr[15];
#pragma unroll
        for (int t = 0; t < 15; ++t) wr[t] = splat(w6[t]);
        f2 bias = splat(b6[0]);
        f2 t0 = bias, t1 = bias;
#pragma unroll
        for (int ci = 0; ci < 5; ++ci) {
            t0 = pf(wr[ci * 3 + 0], hb[ci][0], t0);
            t0 = pf(wr[ci * 3 + 1], hb[ci][1], t0);
            t0 = pf(wr[ci * 3 + 2], hb[ci][2], t0);
            t1 = pf(wr[ci * 3 + 0], hb[ci][1], t1);
            t1 = pf(wr[ci * 3 + 1], hb[ci][2], t1);
            t1 = pf(wr[ci * 3 + 2], hb[ci][3], t1);
        }
        t0 = relu2(t0);
        t1 = relu2(t1);
        f2 o;
        o.x = 0.5f * (t0.x + t1.x);
        o.y = 0.5f * (t0.y + t1.y);
        zout[(size_t)n0 * BB + lane]       = o.x;
        zout[(size_t)(n0 + 1) * BB + lane] = o.y;
    }
}

// ---------------------------------------------------------------------------
// Final driver gather: out[b, i] = z[driver_idx[i], b]   (out is (B, NDRV))
__global__ __launch_bounds__(256) void gather_out_kernel(
    const float* __restrict__ z, const int* __restrict__ didx,
    float* __restrict__ out)
{
    int i = blockIdx.x * 256 + threadIdx.x;
    if (i >= BB * NDRVN) return;
    int b = i / NDRVN;
    int k = i - b * NDRVN;
    out[i] = z[(size_t)didx[k] * BB + b];
}

// ---------------------------------------------------------------------------
extern "C" void kernel_launch(void* const* d_in, const int* in_sizes, int n_in,
                              void* d_out, int out_size, void* d_ws, size_t ws_size,
                              hipStream_t stream)
{
    const float* x    = (const float*)d_in[0];
    const int*   nidx = (const int*)  d_in[1];
    const int*   didx = (const int*)  d_in[2];
    const float* w[7];
    const float* b[7];
    for (int i = 0; i < 7; ++i) {
        w[i] = (const float*)d_in[3 + 2 * i];
        b[i] = (const float*)d_in[4 + 2 * i];
    }

    // Workspace: two ping-pong z buffers in (N, B) layout, 12.8 MB each.
    float* z0 = (float*)d_ws;
    float* z1 = z0 + (size_t)NB * BB;

    const int tblocks = (NB * BB) / 256;   // 12500 (transpose)
    const int pblocks = NB / 8;            // 6250: 4 waves x 2 nodes

    transpose_kernel<<<tblocks, 256, 0, stream>>>(x, z0);

    pass_kernel<<<pblocks, 256, 0, stream>>>(z0, z1, nidx,
        w[0], b[0], w[1], b[1], w[2], b[2], w[3], b[3],
        w[4], b[4], w[5], b[5], w[6], b[6]);
    pass_kernel<<<pblocks, 256, 0, stream>>>(z1, z0, nidx,
        w[0], b[0], w[1], b[1], w[2], b[2], w[3], b[3],
        w[4], b[4], w[5], b[5], w[6], b[6]);
    pass_kernel<<<pblocks, 256, 0, stream>>>(z0, z1, nidx,
        w[0], b[0], w[1], b[1], w[2], b[2], w[3], b[3],
        w[4], b[4], w[5], b[5], w[6], b[6]);
    pass_kernel<<<pblocks, 256, 0, stream>>>(z1, z0, nidx,
        w[0], b[0], w[1], b[1], w[2], b[2], w[3], b[3],
        w[4], b[4], w[5], b[5], w[6], b[6]);

    gather_out_kernel<<<(BB * NDRVN + 255) / 256, 256, 0, stream>>>(z0, didx, (float*)d_out);
}